// Round 8
// baseline (599.720 us; speedup 1.0000x reference)
//
#include <hip/hip_runtime.h>

// ---------------------------------------------------------------------------
// WindowAttention: x[2048,49,512] fp32 -> out[2048,49,512] fp32
// R1: T2 LDS XOR-swizzle + T1 XCD swizzle (bank conflicts -> 0).   [593us]
// R2: 8-phase 256^2 port REGRESSED (K=512 too shallow) - reverted.
// R3: fused x-cvt + raw s_barrier guard -> RACE (raw barrier is no fence).
// R4: fused x-cvt reg-staged -> 480us (compiler sinks prefetch). Reverted.
// R5: counted-vmcnt 2-deep pipeline -> NEUTRAL. GEMM schedule plateaued.
// R6: wave-per-head attention (-27us).                             [575us]
// R7: cvt-x killed: GEMM1 stages A as f32 via gload_lds (16-chunk XOR
//     swizzle key row&15) + cvt at frag-read. qkv now token-major
//     [B,N,3*H*d] -> trivial coalesced GEMM1 epilogue; attn re-addressed.
// ---------------------------------------------------------------------------

typedef unsigned short ushort_t;
typedef __bf16 bf16x8 __attribute__((ext_vector_type(8)));
typedef float f32x4 __attribute__((ext_vector_type(4)));
typedef unsigned short us8 __attribute__((ext_vector_type(8)));

#define SCALE_F 0.17677669529663687f   // 32^-0.5

// RNE float -> bf16 (as raw ushort)
__device__ __forceinline__ ushort_t f2bf(float f) {
  unsigned u = __builtin_bit_cast(unsigned, f);
  u += 0x7FFFu + ((u >> 16) & 1u);
  return (ushort_t)(u >> 16);
}

// async global->LDS, 16B per lane; lds base must be wave-uniform
__device__ __forceinline__ void gload_lds16(const void* g, void* l) {
  __builtin_amdgcn_global_load_lds(
      (const __attribute__((address_space(1))) void*)g,
      (__attribute__((address_space(3))) void*)l, 16, 0, 0);
}

// ---------------------------------------------------------------------------
// fp32 -> bf16 conversion (weights only), 4 elems/thread
// ---------------------------------------------------------------------------
__global__ __launch_bounds__(256) void k_cvt(const float* __restrict__ in,
                                             ushort_t* __restrict__ out, int n4) {
  int i = blockIdx.x * blockDim.x + threadIdx.x;
  if (i >= n4) return;
  float4 v = reinterpret_cast<const float4*>(in)[i];
  ushort4 o = make_ushort4(f2bf(v.x), f2bf(v.y), f2bf(v.z), f2bf(v.w));
  reinterpret_cast<ushort4*>(out)[i] = o;
}

// ---------------------------------------------------------------------------
// GEMM1 fused-cvt: qkv[t][o] = sum_k bf16(X[t][k]) * W[o][k] + bias[o].
// X fp32 [100352,512]; W bf16 [1536,512]; out token-major [100352][1536] bf16.
// Tile 128x128, BK=64, 4 waves.
// A staged as RAW F32 via gload_lds into Asf[128][64] f32 (256B rows,
//   16 chunks of 16B; slot(row,c) holds logical chunk c^(row&15), via
//   pre-swizzled global source). Frag read = 2x ds_read_b128 f32 + hw cvt.
// W staged bf16 as in R1 (8 chunks, key row&7).
// ---------------------------------------------------------------------------
__global__ __launch_bounds__(256) void k_gemm1f(const float* __restrict__ X,
                                                const ushort_t* __restrict__ W,
                                                const float* __restrict__ bias,
                                                ushort_t* __restrict__ out_qkv) {
  __shared__ __align__(16) float    Asf[128][64];
  __shared__ __align__(16) ushort_t Ws[128][64];
  constexpr int nt_o = 12;

  const int tid  = threadIdx.x;
  const int lane = tid & 63;
  const int wv   = tid >> 6;
  const int wr   = wv >> 1, wc = wv & 1;

  const int cpx = gridDim.x >> 3;
  const int lid = (blockIdx.x & 7) * cpx + (blockIdx.x >> 3);
  const int bm  = lid / nt_o;
  const int bo  = lid - bm * nt_o;
  const size_t m0 = (size_t)bm * 128;
  const int o0    = bo * 128;

  f32x4 acc[4][4];
#pragma unroll
  for (int i = 0; i < 4; i++)
#pragma unroll
    for (int j = 0; j < 4; j++) acc[i][j] = f32x4{0.f, 0.f, 0.f, 0.f};

  // A staging (f32): call i covers rows wv*32 + i*4 + (lane>>4), slot chunk
  // lane&15; logical chunk = (lane&15) ^ ((i*4 + lane>>4) & 15). Key period 4.
  const int l15 = lane & 15;
  const int lq  = lane >> 4;
  int schA[4];
#pragma unroll
  for (int i = 0; i < 4; i++)
    schA[i] = (l15 ^ ((i * 4 + lq) & 15)) * 4;   // f32-elem offset

  // W staging (bf16, R1-proven): pre-swizzled source, key row&7
  const int srowW = wv * 32 + (lane >> 3);
  const int schW  = ((lane & 7) ^ (lane >> 3)) * 8;
  const ushort_t* Wg = W + (size_t)(o0 + srowW) * 512 + schW;

  for (int kt = 0; kt < 8; ++kt) {
    const int k0 = kt * 64;
#pragma unroll
    for (int i = 0; i < 8; i++) {
      const float* g = X + (m0 + wv * 32 + i * 4 + lq) * 512 + k0 + schA[i & 3];
      gload_lds16(g, &Asf[wv * 32 + i * 4][0]);
    }
#pragma unroll
    for (int i = 0; i < 4; i++)
      gload_lds16(Wg + (size_t)i * (8 * 512) + k0, &Ws[wv * 32 + i * 8][0]);
    __syncthreads();

    const int fr = lane & 15;
#pragma unroll
    for (int kk = 0; kk < 2; ++kk) {
      // W fragments (unchanged bf16 path)
      const int cbW = (((kk * 4 + lq) ^ (lane & 7)) << 3);
      uint4 br[4];
#pragma unroll
      for (int ni = 0; ni < 4; ni++)
        br[ni] = *reinterpret_cast<const uint4*>(&Ws[wc * 64 + ni * 16 + fr][cbW]);
      // A fragments: two f32x4 LDS reads + hw cvt -> bf16x8
      bf16x8 ar[4];
      const int L0 = kk * 8 + lq * 2;
      const int s0 = (L0 ^ fr) * 4;
      const int s1 = ((L0 + 1) ^ fr) * 4;
#pragma unroll
      for (int mi = 0; mi < 4; mi++) {
        const float4 fa = *reinterpret_cast<const float4*>(&Asf[wr * 64 + mi * 16 + fr][s0]);
        const float4 fb = *reinterpret_cast<const float4*>(&Asf[wr * 64 + mi * 16 + fr][s1]);
        bf16x8 t;
        t[0] = (__bf16)fa.x; t[1] = (__bf16)fa.y; t[2] = (__bf16)fa.z; t[3] = (__bf16)fa.w;
        t[4] = (__bf16)fb.x; t[5] = (__bf16)fb.y; t[6] = (__bf16)fb.z; t[7] = (__bf16)fb.w;
        ar[mi] = t;
      }
#pragma unroll
      for (int mi = 0; mi < 4; mi++)
#pragma unroll
        for (int ni = 0; ni < 4; ni++)
          acc[mi][ni] = __builtin_amdgcn_mfma_f32_16x16x32_bf16(
              ar[mi], __builtin_bit_cast(bf16x8, br[ni]), acc[mi][ni], 0, 0, 0);
    }
    __syncthreads();
  }

  // epilogue: token-major, coalesced
  const int colbase = lane & 15;
  const int rowgrp  = (lane >> 4) * 4;
#pragma unroll
  for (int mi = 0; mi < 4; mi++) {
#pragma unroll
    for (int r = 0; r < 4; r++) {
      const size_t t = m0 + wr * 64 + mi * 16 + rowgrp + r;
      ushort_t* rowp = out_qkv + t * 1536;
#pragma unroll
      for (int ni = 0; ni < 4; ni++) {
        const int o = o0 + wc * 64 + ni * 16 + colbase;
        rowp[o] = f2bf(acc[mi][ni][r] + bias[o]);
      }
    }
  }
}

// ---------------------------------------------------------------------------
// GEMM2: out[m][o] = sum_k A[m][k]*W[o][k] + bias[o]  (bf16 in, fp32 out)
// R1-proven structure, unchanged.
// ---------------------------------------------------------------------------
__global__ __launch_bounds__(256) void k_gemmB(const ushort_t* __restrict__ A,
                                               const ushort_t* __restrict__ W,
                                               const float* __restrict__ bias,
                                               float* __restrict__ out_f,
                                               int nt_o) {
  __shared__ __align__(16) ushort_t As[128][64];
  __shared__ __align__(16) ushort_t Ws[128][64];

  const int tid  = threadIdx.x;
  const int lane = tid & 63;
  const int wv   = tid >> 6;
  const int wr   = wv >> 1, wc = wv & 1;

  const int cpx = gridDim.x >> 3;
  const int lid = (blockIdx.x & 7) * cpx + (blockIdx.x >> 3);
  const int bm  = lid / nt_o;
  const int bo  = lid - bm * nt_o;
  const size_t m0 = (size_t)bm * 128;
  const int o0    = bo * 128;

  f32x4 acc[4][4];
#pragma unroll
  for (int i = 0; i < 4; i++)
#pragma unroll
    for (int j = 0; j < 4; j++) acc[i][j] = f32x4{0.f, 0.f, 0.f, 0.f};

  const int srow   = wv * 32 + (lane >> 3);
  const int schunk = (((lane & 7) ^ (lane >> 3)) * 8);

  for (int kt = 0; kt < 8; ++kt) {
    const int k0 = kt * 64;
#pragma unroll
    for (int i = 0; i < 4; i++)
      gload_lds16(A + (m0 + srow + i * 8) * 512 + k0 + schunk,
                  &As[wv * 32 + i * 8][0]);
#pragma unroll
    for (int i = 0; i < 4; i++)
      gload_lds16(W + (size_t)(o0 + srow + i * 8) * 512 + k0 + schunk,
                  &Ws[wv * 32 + i * 8][0]);
    __syncthreads();
    const int fr = lane & 15;
#pragma unroll
    for (int kk = 0; kk < 2; ++kk) {
      const int ch = kk * 4 + (lane >> 4);
      const int cb = ((ch ^ (lane & 7)) << 3);
      uint4 ar[4], br[4];
#pragma unroll
      for (int mi = 0; mi < 4; mi++)
        ar[mi] = *reinterpret_cast<const uint4*>(&As[wr * 64 + mi * 16 + fr][cb]);
#pragma unroll
      for (int ni = 0; ni < 4; ni++)
        br[ni] = *reinterpret_cast<const uint4*>(&Ws[wc * 64 + ni * 16 + fr][cb]);
#pragma unroll
      for (int mi = 0; mi < 4; mi++)
#pragma unroll
        for (int ni = 0; ni < 4; ni++)
          acc[mi][ni] = __builtin_amdgcn_mfma_f32_16x16x32_bf16(
              __builtin_bit_cast(bf16x8, ar[mi]),
              __builtin_bit_cast(bf16x8, br[ni]), acc[mi][ni], 0, 0, 0);
    }
    __syncthreads();
  }

  const int colbase = lane & 15;
  const int rowgrp  = (lane >> 4) * 4;
#pragma unroll
  for (int ni = 0; ni < 4; ni++) {
    const int o = o0 + wc * 64 + ni * 16 + colbase;
    const float bv = bias[o];
#pragma unroll
    for (int mi = 0; mi < 4; mi++) {
      const size_t mrow = m0 + wr * 64 + mi * 16 + rowgrp;
#pragma unroll
      for (int r = 0; r < 4; r++)
        out_f[(mrow + r) * 512 + o] = acc[mi][ni][r] + bv;
    }
  }
}

// ---------------------------------------------------------------------------
// Attention (R6 wave-per-head), re-addressed for token-major qkv:
// q row t=b*49+n at qkv[t*1536 + h*32 + d]; k at +512; v at +1024.
// OOB tail rows (n in 49..63 of last batch) stay inside d_ws and are
// masked (S) / never loaded (V) -> safe.
// ---------------------------------------------------------------------------
__global__ __launch_bounds__(256) void k_attn4(const ushort_t* __restrict__ qkv,
                                               const float* __restrict__ mask,
                                               ushort_t* __restrict__ aout) {
  __shared__ __align__(16) ushort_t Vt[4][32][64];   // per-wave V^T (swizzled)
  __shared__ __align__(16) ushort_t Ps[4][64][64];   // per-wave P (swizzled)

  const int tid  = threadIdx.x;
  const int lane = tid & 63;
  const int wv   = tid >> 6;
  const int blk  = blockIdx.x;
  const int b    = blk >> 2;
  const int h    = (blk & 3) * 4 + wv;
  const int w    = b & 63;
  const size_t tb = (size_t)b * 49 * 1536 + (size_t)h * 32;
  const ushort_t* qb = qkv + tb;          // + n*1536 + d
  const ushort_t* kb = qkv + tb + 512;
  const ushort_t* vb = qkv + tb + 1024;

  {
    uint4* vz = reinterpret_cast<uint4*>(&Vt[wv][0][0]);
#pragma unroll
    for (int i = 0; i < 4; i++) vz[i * 64 + lane] = make_uint4(0, 0, 0, 0);
  }
  __syncthreads();
#pragma unroll
  for (int i = 0; i < 4; i++) {
    const int e = lane + (i << 6);
    if (e < 196) {
      const int n = e >> 2, d0 = (e & 3) * 8;
      uint4 raw = *reinterpret_cast<const uint4*>(vb + (size_t)n * 1536 + d0);
      us8 ev = __builtin_bit_cast(us8, raw);
#pragma unroll
      for (int j = 0; j < 8; j++)
        Vt[wv][d0 + j][(((n >> 3) ^ j) << 3) | (n & 7)] = ev[j];
    }
  }

  const int arow = lane & 15;
  const int kc   = (lane >> 4) * 8;
  const int rg   = (lane >> 4) * 4;

  uint4 kf[4];
#pragma unroll
  for (int ni = 0; ni < 4; ni++)
    kf[ni] = *reinterpret_cast<const uint4*>(kb + (size_t)(ni * 16 + arow) * 1536 + kc);

  float rsum[4][4];

#pragma unroll
  for (int hm = 0; hm < 2; hm++) {
    f32x4 s2[2][4];
#pragma unroll
    for (int j = 0; j < 2; j++) {
      const int mt = hm * 2 + j;
      uint4 qraw = *reinterpret_cast<const uint4*>(qb + (size_t)(mt * 16 + arow) * 1536 + kc);
      bf16x8 qa = __builtin_bit_cast(bf16x8, qraw);
#pragma unroll
      for (int ni = 0; ni < 4; ni++) {
        f32x4 z = {0.f, 0.f, 0.f, 0.f};
        s2[j][ni] = __builtin_amdgcn_mfma_f32_16x16x32_bf16(
            qa, __builtin_bit_cast(bf16x8, kf[ni]), z, 0, 0, 0);
      }
    }
#pragma unroll
    for (int j = 0; j < 2; j++) {
      const int mt = hm * 2 + j;
#pragma unroll
      for (int r = 0; r < 4; r++) {
        const int qr = mt * 16 + rg + r;
        float sv[4];
        float mx = -1e30f;
#pragma unroll
        for (int ni = 0; ni < 4; ni++) {
          const int col = ni * 16 + arow;
          float v;
          if (qr < 49 && col < 49)
            v = s2[j][ni][r] * SCALE_F + mask[(size_t)w * 2401 + qr * 49 + col];
          else
            v = -1e30f;
          sv[ni] = v;
          mx = fmaxf(mx, v);
        }
#pragma unroll
        for (int off = 1; off < 16; off <<= 1) mx = fmaxf(mx, __shfl_xor(mx, off));
        float sum = 0.f;
        const int prow = rg + r;
#pragma unroll
        for (int ni = 0; ni < 4; ni++) {
          float p = __expf(sv[ni] - mx);
          sum += p;
          const int pcol = ni * 16 + arow;
          Ps[wv][mt * 16 + prow]
            [(((pcol >> 3) ^ (prow & 7)) << 3) | (pcol & 7)] = f2bf(p);
        }
#pragma unroll
        for (int off = 1; off < 16; off <<= 1) sum += __shfl_xor(sum, off);
        rsum[mt][r] = sum;
      }
    }
  }

  __syncthreads();   // fence Vt + Ps writes before uint4 reads

  uint4 vf0[2], vf1[2];
#pragma unroll
  for (int kk = 0; kk < 2; kk++) {
    const int ch = kk * 4 + (lane >> 4);
    const int cb = ((ch ^ (lane & 7)) << 3);
    vf0[kk] = *reinterpret_cast<const uint4*>(&Vt[wv][arow][cb]);
    vf1[kk] = *reinterpret_cast<const uint4*>(&Vt[wv][16 + arow][cb]);
  }

#pragma unroll
  for (int mt = 0; mt < 4; mt++) {
    f32x4 o0 = {0.f, 0.f, 0.f, 0.f}, o1 = {0.f, 0.f, 0.f, 0.f};
#pragma unroll
    for (int kk = 0; kk < 2; kk++) {
      const int ch = kk * 4 + (lane >> 4);
      const int cb = ((ch ^ (lane & 7)) << 3);
      uint4 praw = *reinterpret_cast<const uint4*>(&Ps[wv][mt * 16 + arow][cb]);
      bf16x8 pa = __builtin_bit_cast(bf16x8, praw);
      o0 = __builtin_amdgcn_mfma_f32_16x16x32_bf16(
          pa, __builtin_bit_cast(bf16x8, vf0[kk]), o0, 0, 0, 0);
      o1 = __builtin_amdgcn_mfma_f32_16x16x32_bf16(
          pa, __builtin_bit_cast(bf16x8, vf1[kk]), o1, 0, 0, 0);
    }
#pragma unroll
    for (int r = 0; r < 4; r++) {
      const int qr = mt * 16 + rg + r;
      if (qr < 49) {
        const float inv = 1.f / rsum[mt][r];
        aout[((size_t)b * 49 + qr) * 512 + h * 32 + arow]      = f2bf(o0[r] * inv);
        aout[((size_t)b * 49 + qr) * 512 + h * 32 + 16 + arow] = f2bf(o1[r] * inv);
      }
    }
  }
}

// ---------------------------------------------------------------------------
// launch
// ---------------------------------------------------------------------------
extern "C" void kernel_launch(void* const* d_in, const int* in_sizes, int n_in,
                              void* d_out, int out_size, void* d_ws, size_t ws_size,
                              hipStream_t stream) {
  const float* x      = (const float*)d_in[0];
  const float* mask   = (const float*)d_in[1];
  const float* W_qkv  = (const float*)d_in[2];
  const float* b_qkv  = (const float*)d_in[3];
  const float* W_proj = (const float*)d_in[4];
  const float* b_proj = (const float*)d_in[5];
  float* out = (float*)d_out;

  // ws layout (bf16 elems): qkv token-major [100352][1536] | attn_out | weights
  ushort_t* ws     = (ushort_t*)d_ws;
  ushort_t* qkvb   = ws;                                  // 154,140,672
  ushort_t* aoutb  = ws + 154140672UL;                    // 51,380,224
  ushort_t* wqkvb  = ws + 205520896UL;                    // 786,432
  ushort_t* wprojb = ws + 206307328UL;                    // 262,144

  const int n4q = 786432 / 4, n4p = 262144 / 4;
  k_cvt<<<(n4q + 255) / 256, 256, 0, stream>>>(W_qkv, wqkvb, n4q);
  k_cvt<<<(n4p + 255) / 256, 256, 0, stream>>>(W_proj, wprojb, n4p);

  // GEMM1 (A staged f32, fused cvt): [100352,512]f32 x [1536,512]^T -> qkv.
  k_gemm1f<<<784 * 12, 256, 0, stream>>>(x, wqkvb, b_qkv, qkvb);

  // attention: block = 4 heads, wave = 1 head
  k_attn4<<<2048 * 4, 256, 0, stream>>>(qkvb, mask, aoutb);

  // GEMM2: [100352,512] x [512,512]^T + bias -> fp32 out.
  k_gemmB<<<784 * 4, 256, 0, stream>>>(aoutb, wprojb, b_proj, out, 4);
}

// Round 9
// 573.147 us; speedup vs baseline: 1.0464x; 1.0464x over previous
//
#include <hip/hip_runtime.h>

// ---------------------------------------------------------------------------
// WindowAttention: x[2048,49,512] fp32 -> out[2048,49,512] fp32
// R1: T2 LDS XOR-swizzle + T1 XCD swizzle (bank conflicts -> 0).   [593us]
// R2: 8-phase 256^2 port REGRESSED (K=512 too shallow) - reverted.
// R3: fused x-cvt + raw s_barrier guard -> RACE (raw barrier is no fence).
// R4: fused x-cvt reg-staged -> 480us. Reverted.
// R5: counted-vmcnt 2-deep pipeline -> NEUTRAL. GEMM schedule plateaued.
// R6: wave-per-head attention (-27us).                             [575us]
// R7: f32-A-staged GEMM1 -> 357us REGRESSED (2x LDS reads + cvt on critical
//     path). Reverted to bf16 staging + separate cvt-x. Token-major KEPT.
// R8: attention softmax de-cross-laned: no max-subtract (scores bounded),
//     rowsum via all-ones MFMA B-fragment (denominator from matrix pipe).
// ---------------------------------------------------------------------------

typedef unsigned short ushort_t;
typedef __bf16 bf16x8 __attribute__((ext_vector_type(8)));
typedef float f32x4 __attribute__((ext_vector_type(4)));
typedef unsigned short us8 __attribute__((ext_vector_type(8)));

#define SCALE_F 0.17677669529663687f   // 32^-0.5

// RNE float -> bf16 (as raw ushort)
__device__ __forceinline__ ushort_t f2bf(float f) {
  unsigned u = __builtin_bit_cast(unsigned, f);
  u += 0x7FFFu + ((u >> 16) & 1u);
  return (ushort_t)(u >> 16);
}

// async global->LDS, 16B per lane; lds base must be wave-uniform
__device__ __forceinline__ void gload_lds16(const void* g, void* l) {
  __builtin_amdgcn_global_load_lds(
      (const __attribute__((address_space(1))) void*)g,
      (__attribute__((address_space(3))) void*)l, 16, 0, 0);
}

// ---------------------------------------------------------------------------
// fp32 -> bf16 conversion, 4 elems/thread
// ---------------------------------------------------------------------------
__global__ __launch_bounds__(256) void k_cvt(const float* __restrict__ in,
                                             ushort_t* __restrict__ out, int n4) {
  int i = blockIdx.x * blockDim.x + threadIdx.x;
  if (i >= n4) return;
  float4 v = reinterpret_cast<const float4*>(in)[i];
  ushort4 o = make_ushort4(f2bf(v.x), f2bf(v.y), f2bf(v.z), f2bf(v.w));
  reinterpret_cast<ushort4*>(out)[i] = o;
}

// ---------------------------------------------------------------------------
// GEMM1 (R6-proven bits): qkv[t][o] = sum_k A[t][k]*W[o][k] + bias[o].
// A,W bf16 row-major K=512. 128x128 tile, BK=64, 4 waves, gload_lds staging,
// XOR-swizzled LDS (slot(row,c) holds chunk c^(row&7), pre-swizzled source).
// Epilogue: token-major [100352][1536] bf16, coalesced.
// ---------------------------------------------------------------------------
__global__ __launch_bounds__(256) void k_gemm1(const ushort_t* __restrict__ A,
                                               const ushort_t* __restrict__ W,
                                               const float* __restrict__ bias,
                                               ushort_t* __restrict__ out_qkv) {
  __shared__ __align__(16) ushort_t As[128][64];
  __shared__ __align__(16) ushort_t Ws[128][64];
  constexpr int nt_o = 12;

  const int tid  = threadIdx.x;
  const int lane = tid & 63;
  const int wv   = tid >> 6;
  const int wr   = wv >> 1, wc = wv & 1;

  const int cpx = gridDim.x >> 3;
  const int lid = (blockIdx.x & 7) * cpx + (blockIdx.x >> 3);
  const int bm  = lid / nt_o;
  const int bo  = lid - bm * nt_o;
  const size_t m0 = (size_t)bm * 128;
  const int o0    = bo * 128;

  f32x4 acc[4][4];
#pragma unroll
  for (int i = 0; i < 4; i++)
#pragma unroll
    for (int j = 0; j < 4; j++) acc[i][j] = f32x4{0.f, 0.f, 0.f, 0.f};

  const int srow   = wv * 32 + (lane >> 3);
  const int schunk = (((lane & 7) ^ (lane >> 3)) * 8);

  for (int kt = 0; kt < 8; ++kt) {
    const int k0 = kt * 64;
#pragma unroll
    for (int i = 0; i < 4; i++)
      gload_lds16(A + (m0 + srow + i * 8) * 512 + k0 + schunk,
                  &As[wv * 32 + i * 8][0]);
#pragma unroll
    for (int i = 0; i < 4; i++)
      gload_lds16(W + (size_t)(o0 + srow + i * 8) * 512 + k0 + schunk,
                  &Ws[wv * 32 + i * 8][0]);
    __syncthreads();
    const int fr = lane & 15;
#pragma unroll
    for (int kk = 0; kk < 2; ++kk) {
      const int ch = kk * 4 + (lane >> 4);
      const int cb = ((ch ^ (lane & 7)) << 3);
      uint4 ar[4], br[4];
#pragma unroll
      for (int mi = 0; mi < 4; mi++)
        ar[mi] = *reinterpret_cast<const uint4*>(&As[wr * 64 + mi * 16 + fr][cb]);
#pragma unroll
      for (int ni = 0; ni < 4; ni++)
        br[ni] = *reinterpret_cast<const uint4*>(&Ws[wc * 64 + ni * 16 + fr][cb]);
#pragma unroll
      for (int mi = 0; mi < 4; mi++)
#pragma unroll
        for (int ni = 0; ni < 4; ni++)
          acc[mi][ni] = __builtin_amdgcn_mfma_f32_16x16x32_bf16(
              __builtin_bit_cast(bf16x8, ar[mi]),
              __builtin_bit_cast(bf16x8, br[ni]), acc[mi][ni], 0, 0, 0);
    }
    __syncthreads();
  }

  // epilogue: token-major, coalesced
  const int colbase = lane & 15;
  const int rowgrp  = (lane >> 4) * 4;
#pragma unroll
  for (int mi = 0; mi < 4; mi++) {
#pragma unroll
    for (int r = 0; r < 4; r++) {
      const size_t t = m0 + wr * 64 + mi * 16 + rowgrp + r;
      ushort_t* rowp = out_qkv + t * 1536;
#pragma unroll
      for (int ni = 0; ni < 4; ni++) {
        const int o = o0 + wc * 64 + ni * 16 + colbase;
        rowp[o] = f2bf(acc[mi][ni][r] + bias[o]);
      }
    }
  }
}

// ---------------------------------------------------------------------------
// GEMM2: out[m][o] = sum_k A[m][k]*W[o][k] + bias[o]  (bf16 in, fp32 out)
// R1-proven structure, unchanged.
// ---------------------------------------------------------------------------
__global__ __launch_bounds__(256) void k_gemmB(const ushort_t* __restrict__ A,
                                               const ushort_t* __restrict__ W,
                                               const float* __restrict__ bias,
                                               float* __restrict__ out_f,
                                               int nt_o) {
  __shared__ __align__(16) ushort_t As[128][64];
  __shared__ __align__(16) ushort_t Ws[128][64];

  const int tid  = threadIdx.x;
  const int lane = tid & 63;
  const int wv   = tid >> 6;
  const int wr   = wv >> 1, wc = wv & 1;

  const int cpx = gridDim.x >> 3;
  const int lid = (blockIdx.x & 7) * cpx + (blockIdx.x >> 3);
  const int bm  = lid / nt_o;
  const int bo  = lid - bm * nt_o;
  const size_t m0 = (size_t)bm * 128;
  const int o0    = bo * 128;

  f32x4 acc[4][4];
#pragma unroll
  for (int i = 0; i < 4; i++)
#pragma unroll
    for (int j = 0; j < 4; j++) acc[i][j] = f32x4{0.f, 0.f, 0.f, 0.f};

  const int srow   = wv * 32 + (lane >> 3);
  const int schunk = (((lane & 7) ^ (lane >> 3)) * 8);

  for (int kt = 0; kt < 8; ++kt) {
    const int k0 = kt * 64;
#pragma unroll
    for (int i = 0; i < 4; i++)
      gload_lds16(A + (m0 + srow + i * 8) * 512 + k0 + schunk,
                  &As[wv * 32 + i * 8][0]);
#pragma unroll
    for (int i = 0; i < 4; i++)
      gload_lds16(W + (size_t)(o0 + srow + i * 8) * 512 + k0 + schunk,
                  &Ws[wv * 32 + i * 8][0]);
    __syncthreads();
    const int fr = lane & 15;
#pragma unroll
    for (int kk = 0; kk < 2; ++kk) {
      const int ch = kk * 4 + (lane >> 4);
      const int cb = ((ch ^ (lane & 7)) << 3);
      uint4 ar[4], br[4];
#pragma unroll
      for (int mi = 0; mi < 4; mi++)
        ar[mi] = *reinterpret_cast<const uint4*>(&As[wr * 64 + mi * 16 + fr][cb]);
#pragma unroll
      for (int ni = 0; ni < 4; ni++)
        br[ni] = *reinterpret_cast<const uint4*>(&Ws[wc * 64 + ni * 16 + fr][cb]);
#pragma unroll
      for (int mi = 0; mi < 4; mi++)
#pragma unroll
        for (int ni = 0; ni < 4; ni++)
          acc[mi][ni] = __builtin_amdgcn_mfma_f32_16x16x32_bf16(
              __builtin_bit_cast(bf16x8, ar[mi]),
              __builtin_bit_cast(bf16x8, br[ni]), acc[mi][ni], 0, 0, 0);
    }
    __syncthreads();
  }

  const int colbase = lane & 15;
  const int rowgrp  = (lane >> 4) * 4;
#pragma unroll
  for (int ni = 0; ni < 4; ni++) {
    const int o = o0 + wc * 64 + ni * 16 + colbase;
    const float bv = bias[o];
#pragma unroll
    for (int mi = 0; mi < 4; mi++) {
      const size_t mrow = m0 + wr * 64 + mi * 16 + rowgrp;
#pragma unroll
      for (int r = 0; r < 4; r++)
        out_f[(mrow + r) * 512 + o] = acc[mi][ni][r] + bv;
    }
  }
}

// ---------------------------------------------------------------------------
// Attention v3: wave-per-head, token-major qkv [t][1536] (q|k|v at h*32,
// +512, +1024). No cross-lane softmax: p = exp(s*scale+mask) directly
// (scores bounded, shift-invariance), rowsum via all-ones MFMA B-fragment
// in the PV step (o2[r] = rowsum of row rg+r).
// ---------------------------------------------------------------------------
__global__ __launch_bounds__(256) void k_attn4(const ushort_t* __restrict__ qkv,
                                               const float* __restrict__ mask,
                                               ushort_t* __restrict__ aout) {
  __shared__ __align__(16) ushort_t Vt[4][32][64];   // per-wave V^T (swizzled)
  __shared__ __align__(16) ushort_t Ps[4][64][64];   // per-wave P (swizzled)

  const int tid  = threadIdx.x;
  const int lane = tid & 63;
  const int wv   = tid >> 6;
  const int blk  = blockIdx.x;
  const int b    = blk >> 2;
  const int h    = (blk & 3) * 4 + wv;
  const int w    = b & 63;
  const size_t tb = (size_t)b * 49 * 1536 + (size_t)h * 32;
  const ushort_t* qb = qkv + tb;          // + n*1536 + d
  const ushort_t* kb = qkv + tb + 512;
  const ushort_t* vb = qkv + tb + 1024;

  {
    uint4* vz = reinterpret_cast<uint4*>(&Vt[wv][0][0]);
#pragma unroll
    for (int i = 0; i < 4; i++) vz[i * 64 + lane] = make_uint4(0, 0, 0, 0);
  }
  __syncthreads();
#pragma unroll
  for (int i = 0; i < 4; i++) {
    const int e = lane + (i << 6);
    if (e < 196) {
      const int n = e >> 2, d0 = (e & 3) * 8;
      uint4 raw = *reinterpret_cast<const uint4*>(vb + (size_t)n * 1536 + d0);
      us8 ev = __builtin_bit_cast(us8, raw);
#pragma unroll
      for (int j = 0; j < 8; j++)
        Vt[wv][d0 + j][(((n >> 3) ^ j) << 3) | (n & 7)] = ev[j];
    }
  }

  const int arow = lane & 15;
  const int kc   = (lane >> 4) * 8;
  const int rg   = (lane >> 4) * 4;

  uint4 kf[4];
#pragma unroll
  for (int ni = 0; ni < 4; ni++)
    kf[ni] = *reinterpret_cast<const uint4*>(kb + (size_t)(ni * 16 + arow) * 1536 + kc);

  // S + P in two halves (mt = 2*hm + j); no reductions, no running max
#pragma unroll
  for (int hm = 0; hm < 2; hm++) {
    f32x4 s2[2][4];
#pragma unroll
    for (int j = 0; j < 2; j++) {
      const int mt = hm * 2 + j;
      uint4 qraw = *reinterpret_cast<const uint4*>(qb + (size_t)(mt * 16 + arow) * 1536 + kc);
      bf16x8 qa = __builtin_bit_cast(bf16x8, qraw);
#pragma unroll
      for (int ni = 0; ni < 4; ni++) {
        f32x4 z = {0.f, 0.f, 0.f, 0.f};
        s2[j][ni] = __builtin_amdgcn_mfma_f32_16x16x32_bf16(
            qa, __builtin_bit_cast(bf16x8, kf[ni]), z, 0, 0, 0);
      }
    }
#pragma unroll
    for (int j = 0; j < 2; j++) {
      const int mt = hm * 2 + j;
#pragma unroll
      for (int r = 0; r < 4; r++) {
        const int qr = mt * 16 + rg + r;
        const int prow = rg + r;
#pragma unroll
        for (int ni = 0; ni < 4; ni++) {
          const int col = ni * 16 + arow;
          float p;
          if (qr < 49 && col < 49)
            p = __expf(s2[j][ni][r] * SCALE_F + mask[(size_t)w * 2401 + qr * 49 + col]);
          else
            p = 0.f;
          const int pcol = ni * 16 + arow;
          Ps[wv][mt * 16 + prow]
            [(((pcol >> 3) ^ (prow & 7)) << 3) | (pcol & 7)] = f2bf(p);
        }
      }
    }
  }

  __syncthreads();   // fence Vt + Ps writes before uint4 reads

  uint4 vf0[2], vf1[2];
#pragma unroll
  for (int kk = 0; kk < 2; kk++) {
    const int ch = kk * 4 + (lane >> 4);
    const int cb = ((ch ^ (lane & 7)) << 3);
    vf0[kk] = *reinterpret_cast<const uint4*>(&Vt[wv][arow][cb]);
    vf1[kk] = *reinterpret_cast<const uint4*>(&Vt[wv][16 + arow][cb]);
  }

  bf16x8 ones;
#pragma unroll
  for (int i = 0; i < 8; i++) ones[i] = (__bf16)1.0f;

#pragma unroll
  for (int mt = 0; mt < 4; mt++) {
    f32x4 o0 = {0.f, 0.f, 0.f, 0.f}, o1 = {0.f, 0.f, 0.f, 0.f};
    f32x4 o2 = {0.f, 0.f, 0.f, 0.f};   // rowsum accumulator
#pragma unroll
    for (int kk = 0; kk < 2; kk++) {
      const int ch = kk * 4 + (lane >> 4);
      const int cb = ((ch ^ (lane & 7)) << 3);
      uint4 praw = *reinterpret_cast<const uint4*>(&Ps[wv][mt * 16 + arow][cb]);
      bf16x8 pa = __builtin_bit_cast(bf16x8, praw);
      o0 = __builtin_amdgcn_mfma_f32_16x16x32_bf16(
          pa, __builtin_bit_cast(bf16x8, vf0[kk]), o0, 0, 0, 0);
      o1 = __builtin_amdgcn_mfma_f32_16x16x32_bf16(
          pa, __builtin_bit_cast(bf16x8, vf1[kk]), o1, 0, 0, 0);
      o2 = __builtin_amdgcn_mfma_f32_16x16x32_bf16(pa, ones, o2, 0, 0, 0);
    }
#pragma unroll
    for (int r = 0; r < 4; r++) {
      const int qr = mt * 16 + rg + r;
      if (qr < 49) {
        const float inv = 1.f / o2[r];
        aout[((size_t)b * 49 + qr) * 512 + h * 32 + arow]      = f2bf(o0[r] * inv);
        aout[((size_t)b * 49 + qr) * 512 + h * 32 + 16 + arow] = f2bf(o1[r] * inv);
      }
    }
  }
}

// ---------------------------------------------------------------------------
// launch
// ---------------------------------------------------------------------------
extern "C" void kernel_launch(void* const* d_in, const int* in_sizes, int n_in,
                              void* d_out, int out_size, void* d_ws, size_t ws_size,
                              hipStream_t stream) {
  const float* x      = (const float*)d_in[0];
  const float* mask   = (const float*)d_in[1];
  const float* W_qkv  = (const float*)d_in[2];
  const float* b_qkv  = (const float*)d_in[3];
  const float* W_proj = (const float*)d_in[4];
  const float* b_proj = (const float*)d_in[5];
  float* out = (float*)d_out;

  // ws layout (bf16 elems): xb | qkv token-major | attn_out | Wqkv_b | Wproj_b
  ushort_t* ws     = (ushort_t*)d_ws;
  ushort_t* xb     = ws;                                  // 51,380,224
  ushort_t* qkvb   = ws + 51380224UL;                     // 154,140,672
  ushort_t* aoutb  = ws + 205520896UL;                    // 51,380,224
  ushort_t* wqkvb  = ws + 256901120UL;                    // 786,432
  ushort_t* wprojb = ws + 257687552UL;                    // 262,144

  const int n4x = 51380224 / 4, n4q = 786432 / 4, n4p = 262144 / 4;
  k_cvt<<<(n4x + 255) / 256, 256, 0, stream>>>(x, xb, n4x);
  k_cvt<<<(n4q + 255) / 256, 256, 0, stream>>>(W_qkv, wqkvb, n4q);
  k_cvt<<<(n4p + 255) / 256, 256, 0, stream>>>(W_proj, wprojb, n4p);

  // GEMM1: [100352,512] x [1536,512]^T -> token-major qkv.
  k_gemm1<<<784 * 12, 256, 0, stream>>>(xb, wqkvb, b_qkv, qkvb);

  // attention: block = 4 heads, wave = 1 head
  k_attn4<<<2048 * 4, 256, 0, stream>>>(qkvb, mask, aoutb);

  // GEMM2: [100352,512] x [512,512]^T + bias -> fp32 out.
  k_gemmB<<<784 * 4, 256, 0, stream>>>(aoutb, wprojb, b_proj, out, 4);
}

// Round 10
// 559.603 us; speedup vs baseline: 1.0717x; 1.0242x over previous
//
#include <hip/hip_runtime.h>

// ---------------------------------------------------------------------------
// WindowAttention: x[2048,49,512] fp32 -> out[2048,49,512] fp32
// R1: T2 LDS XOR-swizzle + T1 XCD swizzle (bank conflicts -> 0).   [593us]
// R2: 8-phase 256^2 port REGRESSED (K=512 too shallow) - reverted.
// R3: raw s_barrier guard -> RACE (raw barrier is no compiler fence).
// R4: fused x-cvt reg-staged -> 480us. Reverted.
// R5: counted-vmcnt 2-deep pipeline -> NEUTRAL. GEMM schedule plateaued.
// R6: wave-per-head attention (-27us).                             [575us]
// R7: f32-A-staged GEMM1 REGRESSED. Token-major qkv KEPT.
// R8: attn: no max-subtract + ones-MFMA rowsum; GEMM1 epilogue coalesced
//     (274->260). attn ~neutral -> it is LATENCY/OCCUPANCY-bound. [573us]
// R9: attn occupancy: Ps halved [4][32][64] (LDS 48->32KB, 3->4 blocks/CU),
//     ALL __syncthreads removed (buffers are wave-private; in-wave
//     lgkmcnt+sched_barrier fences only), one-mt-at-a-time S for VGPR.
// ---------------------------------------------------------------------------

typedef unsigned short ushort_t;
typedef __bf16 bf16x8 __attribute__((ext_vector_type(8)));
typedef float f32x4 __attribute__((ext_vector_type(4)));
typedef unsigned short us8 __attribute__((ext_vector_type(8)));

#define SCALE_F 0.17677669529663687f   // 32^-0.5

// RNE float -> bf16 (as raw ushort)
__device__ __forceinline__ ushort_t f2bf(float f) {
  unsigned u = __builtin_bit_cast(unsigned, f);
  u += 0x7FFFu + ((u >> 16) & 1u);
  return (ushort_t)(u >> 16);
}

// async global->LDS, 16B per lane; lds base must be wave-uniform
__device__ __forceinline__ void gload_lds16(const void* g, void* l) {
  __builtin_amdgcn_global_load_lds(
      (const __attribute__((address_space(1))) void*)g,
      (__attribute__((address_space(3))) void*)l, 16, 0, 0);
}

// wave-local LDS fence: drain ds ops, and stop scheduler hoisting past it
__device__ __forceinline__ void lds_fence() {
  asm volatile("s_waitcnt lgkmcnt(0)" ::: "memory");
  __builtin_amdgcn_sched_barrier(0);
}

// ---------------------------------------------------------------------------
// fp32 -> bf16 conversion, 4 elems/thread
// ---------------------------------------------------------------------------
__global__ __launch_bounds__(256) void k_cvt(const float* __restrict__ in,
                                             ushort_t* __restrict__ out, int n4) {
  int i = blockIdx.x * blockDim.x + threadIdx.x;
  if (i >= n4) return;
  float4 v = reinterpret_cast<const float4*>(in)[i];
  ushort4 o = make_ushort4(f2bf(v.x), f2bf(v.y), f2bf(v.z), f2bf(v.w));
  reinterpret_cast<ushort4*>(out)[i] = o;
}

// ---------------------------------------------------------------------------
// GEMM1 (R8-proven): qkv[t][o] = sum_k A[t][k]*W[o][k] + bias[o].
// 128x128 tile, BK=64, 4 waves, gload_lds staging, XOR-swizzled LDS.
// Epilogue: token-major [100352][1536] bf16, coalesced.
// ---------------------------------------------------------------------------
__global__ __launch_bounds__(256) void k_gemm1(const ushort_t* __restrict__ A,
                                               const ushort_t* __restrict__ W,
                                               const float* __restrict__ bias,
                                               ushort_t* __restrict__ out_qkv) {
  __shared__ __align__(16) ushort_t As[128][64];
  __shared__ __align__(16) ushort_t Ws[128][64];
  constexpr int nt_o = 12;

  const int tid  = threadIdx.x;
  const int lane = tid & 63;
  const int wv   = tid >> 6;
  const int wr   = wv >> 1, wc = wv & 1;

  const int cpx = gridDim.x >> 3;
  const int lid = (blockIdx.x & 7) * cpx + (blockIdx.x >> 3);
  const int bm  = lid / nt_o;
  const int bo  = lid - bm * nt_o;
  const size_t m0 = (size_t)bm * 128;
  const int o0    = bo * 128;

  f32x4 acc[4][4];
#pragma unroll
  for (int i = 0; i < 4; i++)
#pragma unroll
    for (int j = 0; j < 4; j++) acc[i][j] = f32x4{0.f, 0.f, 0.f, 0.f};

  const int srow   = wv * 32 + (lane >> 3);
  const int schunk = (((lane & 7) ^ (lane >> 3)) * 8);

  for (int kt = 0; kt < 8; ++kt) {
    const int k0 = kt * 64;
#pragma unroll
    for (int i = 0; i < 4; i++)
      gload_lds16(A + (m0 + srow + i * 8) * 512 + k0 + schunk,
                  &As[wv * 32 + i * 8][0]);
#pragma unroll
    for (int i = 0; i < 4; i++)
      gload_lds16(W + (size_t)(o0 + srow + i * 8) * 512 + k0 + schunk,
                  &Ws[wv * 32 + i * 8][0]);
    __syncthreads();
    const int fr = lane & 15;
#pragma unroll
    for (int kk = 0; kk < 2; ++kk) {
      const int ch = kk * 4 + (lane >> 4);
      const int cb = ((ch ^ (lane & 7)) << 3);
      uint4 ar[4], br[4];
#pragma unroll
      for (int mi = 0; mi < 4; mi++)
        ar[mi] = *reinterpret_cast<const uint4*>(&As[wr * 64 + mi * 16 + fr][cb]);
#pragma unroll
      for (int ni = 0; ni < 4; ni++)
        br[ni] = *reinterpret_cast<const uint4*>(&Ws[wc * 64 + ni * 16 + fr][cb]);
#pragma unroll
      for (int mi = 0; mi < 4; mi++)
#pragma unroll
        for (int ni = 0; ni < 4; ni++)
          acc[mi][ni] = __builtin_amdgcn_mfma_f32_16x16x32_bf16(
              __builtin_bit_cast(bf16x8, ar[mi]),
              __builtin_bit_cast(bf16x8, br[ni]), acc[mi][ni], 0, 0, 0);
    }
    __syncthreads();
  }

  const int colbase = lane & 15;
  const int rowgrp  = (lane >> 4) * 4;
#pragma unroll
  for (int mi = 0; mi < 4; mi++) {
#pragma unroll
    for (int r = 0; r < 4; r++) {
      const size_t t = m0 + wr * 64 + mi * 16 + rowgrp + r;
      ushort_t* rowp = out_qkv + t * 1536;
#pragma unroll
      for (int ni = 0; ni < 4; ni++) {
        const int o = o0 + wc * 64 + ni * 16 + colbase;
        rowp[o] = f2bf(acc[mi][ni][r] + bias[o]);
      }
    }
  }
}

// ---------------------------------------------------------------------------
// GEMM2: out[m][o] = sum_k A[m][k]*W[o][k] + bias[o]  (bf16 in, fp32 out)
// R1-proven structure, unchanged.
// ---------------------------------------------------------------------------
__global__ __launch_bounds__(256) void k_gemmB(const ushort_t* __restrict__ A,
                                               const ushort_t* __restrict__ W,
                                               const float* __restrict__ bias,
                                               float* __restrict__ out_f,
                                               int nt_o) {
  __shared__ __align__(16) ushort_t As[128][64];
  __shared__ __align__(16) ushort_t Ws[128][64];

  const int tid  = threadIdx.x;
  const int lane = tid & 63;
  const int wv   = tid >> 6;
  const int wr   = wv >> 1, wc = wv & 1;

  const int cpx = gridDim.x >> 3;
  const int lid = (blockIdx.x & 7) * cpx + (blockIdx.x >> 3);
  const int bm  = lid / nt_o;
  const int bo  = lid - bm * nt_o;
  const size_t m0 = (size_t)bm * 128;
  const int o0    = bo * 128;

  f32x4 acc[4][4];
#pragma unroll
  for (int i = 0; i < 4; i++)
#pragma unroll
    for (int j = 0; j < 4; j++) acc[i][j] = f32x4{0.f, 0.f, 0.f, 0.f};

  const int srow   = wv * 32 + (lane >> 3);
  const int schunk = (((lane & 7) ^ (lane >> 3)) * 8);

  for (int kt = 0; kt < 8; ++kt) {
    const int k0 = kt * 64;
#pragma unroll
    for (int i = 0; i < 4; i++)
      gload_lds16(A + (m0 + srow + i * 8) * 512 + k0 + schunk,
                  &As[wv * 32 + i * 8][0]);
#pragma unroll
    for (int i = 0; i < 4; i++)
      gload_lds16(W + (size_t)(o0 + srow + i * 8) * 512 + k0 + schunk,
                  &Ws[wv * 32 + i * 8][0]);
    __syncthreads();
    const int fr = lane & 15;
#pragma unroll
    for (int kk = 0; kk < 2; ++kk) {
      const int ch = kk * 4 + (lane >> 4);
      const int cb = ((ch ^ (lane & 7)) << 3);
      uint4 ar[4], br[4];
#pragma unroll
      for (int mi = 0; mi < 4; mi++)
        ar[mi] = *reinterpret_cast<const uint4*>(&As[wr * 64 + mi * 16 + fr][cb]);
#pragma unroll
      for (int ni = 0; ni < 4; ni++)
        br[ni] = *reinterpret_cast<const uint4*>(&Ws[wc * 64 + ni * 16 + fr][cb]);
#pragma unroll
      for (int mi = 0; mi < 4; mi++)
#pragma unroll
        for (int ni = 0; ni < 4; ni++)
          acc[mi][ni] = __builtin_amdgcn_mfma_f32_16x16x32_bf16(
              __builtin_bit_cast(bf16x8, ar[mi]),
              __builtin_bit_cast(bf16x8, br[ni]), acc[mi][ni], 0, 0, 0);
    }
    __syncthreads();
  }

  const int colbase = lane & 15;
  const int rowgrp  = (lane >> 4) * 4;
#pragma unroll
  for (int ni = 0; ni < 4; ni++) {
    const int o = o0 + wc * 64 + ni * 16 + colbase;
    const float bv = bias[o];
#pragma unroll
    for (int mi = 0; mi < 4; mi++) {
      const size_t mrow = m0 + wr * 64 + mi * 16 + rowgrp;
#pragma unroll
      for (int r = 0; r < 4; r++)
        out_f[(mrow + r) * 512 + o] = acc[mi][ni][r] + bv;
    }
  }
}

// ---------------------------------------------------------------------------
// Attention v4: wave-per-head, token-major qkv. ALL LDS wave-private ->
// no __syncthreads; wave-local lgkmcnt fences only. Ps is a HALF buffer
// (2 mt-tiles) reused across the two halves -> 32 KB total LDS -> 4 blocks/CU.
// No max-subtract (scores bounded); rowsum via ones-MFMA (R8-proven).
// ---------------------------------------------------------------------------
__global__ __launch_bounds__(256) void k_attn4(const ushort_t* __restrict__ qkv,
                                               const float* __restrict__ mask,
                                               ushort_t* __restrict__ aout) {
  __shared__ __align__(16) ushort_t Vt[4][32][64];   // per-wave V^T (swizzled)
  __shared__ __align__(16) ushort_t Ps[4][32][64];   // per-wave P half-tile

  const int tid  = threadIdx.x;
  const int lane = tid & 63;
  const int wv   = tid >> 6;
  const int blk  = blockIdx.x;
  const int b    = blk >> 2;
  const int h    = (blk & 3) * 4 + wv;
  const int w    = b & 63;
  const size_t tb = (size_t)b * 49 * 1536 + (size_t)h * 32;
  const ushort_t* qb = qkv + tb;          // + n*1536 + d
  const ushort_t* kb = qkv + tb + 512;
  const ushort_t* vb = qkv + tb + 1024;

  // zero own Vt (pad cols must be finite), then transposed V write. All
  // wave-private: DS ops are in-order within a wave, no barrier needed.
  {
    uint4* vz = reinterpret_cast<uint4*>(&Vt[wv][0][0]);
#pragma unroll
    for (int i = 0; i < 4; i++) vz[i * 64 + lane] = make_uint4(0, 0, 0, 0);
  }
#pragma unroll
  for (int i = 0; i < 4; i++) {
    const int e = lane + (i << 6);
    if (e < 196) {
      const int n = e >> 2, d0 = (e & 3) * 8;
      uint4 raw = *reinterpret_cast<const uint4*>(vb + (size_t)n * 1536 + d0);
      us8 ev = __builtin_bit_cast(us8, raw);
#pragma unroll
      for (int j = 0; j < 8; j++)
        Vt[wv][d0 + j][(((n >> 3) ^ j) << 3) | (n & 7)] = ev[j];
    }
  }
  lds_fence();   // Vt writes -> vf reads (wave-local)

  const int arow = lane & 15;
  const int kc   = (lane >> 4) * 8;
  const int rg   = (lane >> 4) * 4;

  // V fragments (read once, reused for all mt)
  uint4 vf0[2], vf1[2];
#pragma unroll
  for (int kk = 0; kk < 2; kk++) {
    const int ch = kk * 4 + (lane >> 4);
    const int cb = ((ch ^ (lane & 7)) << 3);
    vf0[kk] = *reinterpret_cast<const uint4*>(&Vt[wv][arow][cb]);
    vf1[kk] = *reinterpret_cast<const uint4*>(&Vt[wv][16 + arow][cb]);
  }

  uint4 kf[4];
#pragma unroll
  for (int ni = 0; ni < 4; ni++)
    kf[ni] = *reinterpret_cast<const uint4*>(kb + (size_t)(ni * 16 + arow) * 1536 + kc);

  bf16x8 ones;
#pragma unroll
  for (int i = 0; i < 8; i++) ones[i] = (__bf16)1.0f;

#pragma unroll
  for (int mt = 0; mt < 4; mt++) {
    // ---- S for this mt, exp, store into half-buffer row (mt&1)*16+prow ----
    {
      uint4 qraw = *reinterpret_cast<const uint4*>(qb + (size_t)(mt * 16 + arow) * 1536 + kc);
      bf16x8 qa = __builtin_bit_cast(bf16x8, qraw);
      f32x4 s[4];
#pragma unroll
      for (int ni = 0; ni < 4; ni++) {
        f32x4 z = {0.f, 0.f, 0.f, 0.f};
        s[ni] = __builtin_amdgcn_mfma_f32_16x16x32_bf16(
            qa, __builtin_bit_cast(bf16x8, kf[ni]), z, 0, 0, 0);
      }
#pragma unroll
      for (int r = 0; r < 4; r++) {
        const int qr = mt * 16 + rg + r;
        const int prow = rg + r;
#pragma unroll
        for (int ni = 0; ni < 4; ni++) {
          const int col = ni * 16 + arow;
          float p;
          if (qr < 49 && col < 49)
            p = __expf(s[ni][r] * SCALE_F + mask[(size_t)w * 2401 + qr * 49 + col]);
          else
            p = 0.f;
          const int pcol = ni * 16 + arow;
          Ps[wv][(mt & 1) * 16 + prow]
            [(((pcol >> 3) ^ (prow & 7)) << 3) | (pcol & 7)] = f2bf(p);
        }
      }
    }

    // ---- every second mt: PV for the pair (mt-1, mt) ----
    if (mt & 1) {
      lds_fence();   // Ps writes -> Ps reads (wave-local)
#pragma unroll
      for (int mh = 0; mh < 2; mh++) {
        const int mtg = (mt - 1) + mh;          // global mt of this tile
        f32x4 o0 = {0.f, 0.f, 0.f, 0.f}, o1 = {0.f, 0.f, 0.f, 0.f};
        f32x4 o2 = {0.f, 0.f, 0.f, 0.f};
#pragma unroll
        for (int kk = 0; kk < 2; kk++) {
          const int ch = kk * 4 + (lane >> 4);
          const int cb = ((ch ^ (lane & 7)) << 3);
          uint4 praw = *reinterpret_cast<const uint4*>(&Ps[wv][mh * 16 + arow][cb]);
          bf16x8 pa = __builtin_bit_cast(bf16x8, praw);
          o0 = __builtin_amdgcn_mfma_f32_16x16x32_bf16(
              pa, __builtin_bit_cast(bf16x8, vf0[kk]), o0, 0, 0, 0);
          o1 = __builtin_amdgcn_mfma_f32_16x16x32_bf16(
              pa, __builtin_bit_cast(bf16x8, vf1[kk]), o1, 0, 0, 0);
          o2 = __builtin_amdgcn_mfma_f32_16x16x32_bf16(pa, ones, o2, 0, 0, 0);
        }
#pragma unroll
        for (int r = 0; r < 4; r++) {
          const int qr = mtg * 16 + rg + r;
          if (qr < 49) {
            const float inv = 1.f / o2[r];
            aout[((size_t)b * 49 + qr) * 512 + h * 32 + arow]      = f2bf(o0[r] * inv);
            aout[((size_t)b * 49 + qr) * 512 + h * 32 + 16 + arow] = f2bf(o1[r] * inv);
          }
        }
      }
      if (mt < 3) lds_fence();   // Ps reads done -> next half may overwrite
    }
  }
}

// ---------------------------------------------------------------------------
// launch
// ---------------------------------------------------------------------------
extern "C" void kernel_launch(void* const* d_in, const int* in_sizes, int n_in,
                              void* d_out, int out_size, void* d_ws, size_t ws_size,
                              hipStream_t stream) {
  const float* x      = (const float*)d_in[0];
  const float* mask   = (const float*)d_in[1];
  const float* W_qkv  = (const float*)d_in[2];
  const float* b_qkv  = (const float*)d_in[3];
  const float* W_proj = (const float*)d_in[4];
  const float* b_proj = (const float*)d_in[5];
  float* out = (float*)d_out;

  // ws layout (bf16 elems): xb | qkv token-major | attn_out | Wqkv_b | Wproj_b
  ushort_t* ws     = (ushort_t*)d_ws;
  ushort_t* xb     = ws;                                  // 51,380,224
  ushort_t* qkvb   = ws + 51380224UL;                     // 154,140,672
  ushort_t* aoutb  = ws + 205520896UL;                    // 51,380,224
  ushort_t* wqkvb  = ws + 256901120UL;                    // 786,432
  ushort_t* wprojb = ws + 257687552UL;                    // 262,144

  const int n4x = 51380224 / 4, n4q = 786432 / 4, n4p = 262144 / 4;
  k_cvt<<<(n4x + 255) / 256, 256, 0, stream>>>(x, xb, n4x);
  k_cvt<<<(n4q + 255) / 256, 256, 0, stream>>>(W_qkv, wqkvb, n4q);
  k_cvt<<<(n4p + 255) / 256, 256, 0, stream>>>(W_proj, wprojb, n4p);

  // GEMM1: [100352,512] x [1536,512]^T -> token-major qkv.
  k_gemm1<<<784 * 12, 256, 0, stream>>>(xb, wqkvb, b_qkv, qkvb);

  // attention: block = 4 heads, wave = 1 head
  k_attn4<<<2048 * 4, 256, 0, stream>>>(qkvb, mask, aoutb);

  // GEMM2: [100352,512] x [512,512]^T + bias -> fp32 out.
  k_gemmB<<<784 * 4, 256, 0, stream>>>(aoutb, wprojb, b_proj, out, 4);
}

// Round 11
// 554.388 us; speedup vs baseline: 1.0818x; 1.0094x over previous
//
#include <hip/hip_runtime.h>

// ---------------------------------------------------------------------------
// WindowAttention: x[2048,49,512] fp32 -> out[2048,49,512] fp32
// R1: T2 LDS XOR-swizzle + T1 XCD swizzle (bank conflicts -> 0).   [593us]
// R2: 8-phase 256^2 port REGRESSED (K=512 too shallow) - reverted.
// R3: raw s_barrier guard -> RACE (raw barrier is no compiler fence).
// R4: fused x-cvt reg-staged -> 480us. Reverted.
// R5: counted-vmcnt 2-deep pipeline -> NEUTRAL. GEMM schedule plateaued.
// R6: wave-per-head attention (-27us).                             [575us]
// R7: f32-A-staged GEMM1 REGRESSED. Token-major qkv KEPT.
// R8: attn: no max-subtract + ones-MFMA rowsum; coalesced GEMM1 epilogue
//     (274->260).                                                  [573us]
// R9: attn: no __syncthreads (wave-private LDS), Ps halved, 48->32KB,
//     4 blocks/CU.                                                 [560us]
// R10: attn occupancy push: Ps quartered [4][16][64] (LDS 24KB -> 5-6
//      blocks/CU), per-mt immediate PV, WAR fence dropped (in-order DS).
// ---------------------------------------------------------------------------

typedef unsigned short ushort_t;
typedef __bf16 bf16x8 __attribute__((ext_vector_type(8)));
typedef float f32x4 __attribute__((ext_vector_type(4)));
typedef unsigned short us8 __attribute__((ext_vector_type(8)));

#define SCALE_F 0.17677669529663687f   // 32^-0.5

// RNE float -> bf16 (as raw ushort)
__device__ __forceinline__ ushort_t f2bf(float f) {
  unsigned u = __builtin_bit_cast(unsigned, f);
  u += 0x7FFFu + ((u >> 16) & 1u);
  return (ushort_t)(u >> 16);
}

// async global->LDS, 16B per lane; lds base must be wave-uniform
__device__ __forceinline__ void gload_lds16(const void* g, void* l) {
  __builtin_amdgcn_global_load_lds(
      (const __attribute__((address_space(1))) void*)g,
      (__attribute__((address_space(3))) void*)l, 16, 0, 0);
}

// wave-local LDS fence: drain ds ops, and stop scheduler hoisting past it
__device__ __forceinline__ void lds_fence() {
  asm volatile("s_waitcnt lgkmcnt(0)" ::: "memory");
  __builtin_amdgcn_sched_barrier(0);
}

// ---------------------------------------------------------------------------
// fp32 -> bf16 conversion, 4 elems/thread
// ---------------------------------------------------------------------------
__global__ __launch_bounds__(256) void k_cvt(const float* __restrict__ in,
                                             ushort_t* __restrict__ out, int n4) {
  int i = blockIdx.x * blockDim.x + threadIdx.x;
  if (i >= n4) return;
  float4 v = reinterpret_cast<const float4*>(in)[i];
  ushort4 o = make_ushort4(f2bf(v.x), f2bf(v.y), f2bf(v.z), f2bf(v.w));
  reinterpret_cast<ushort4*>(out)[i] = o;
}

// ---------------------------------------------------------------------------
// GEMM1 (R8/R9-proven): qkv[t][o] = sum_k A[t][k]*W[o][k] + bias[o].
// 128x128 tile, BK=64, 4 waves, gload_lds staging, XOR-swizzled LDS.
// Epilogue: token-major [100352][1536] bf16, coalesced.
// ---------------------------------------------------------------------------
__global__ __launch_bounds__(256) void k_gemm1(const ushort_t* __restrict__ A,
                                               const ushort_t* __restrict__ W,
                                               const float* __restrict__ bias,
                                               ushort_t* __restrict__ out_qkv) {
  __shared__ __align__(16) ushort_t As[128][64];
  __shared__ __align__(16) ushort_t Ws[128][64];
  constexpr int nt_o = 12;

  const int tid  = threadIdx.x;
  const int lane = tid & 63;
  const int wv   = tid >> 6;
  const int wr   = wv >> 1, wc = wv & 1;

  const int cpx = gridDim.x >> 3;
  const int lid = (blockIdx.x & 7) * cpx + (blockIdx.x >> 3);
  const int bm  = lid / nt_o;
  const int bo  = lid - bm * nt_o;
  const size_t m0 = (size_t)bm * 128;
  const int o0    = bo * 128;

  f32x4 acc[4][4];
#pragma unroll
  for (int i = 0; i < 4; i++)
#pragma unroll
    for (int j = 0; j < 4; j++) acc[i][j] = f32x4{0.f, 0.f, 0.f, 0.f};

  const int srow   = wv * 32 + (lane >> 3);
  const int schunk = (((lane & 7) ^ (lane >> 3)) * 8);

  for (int kt = 0; kt < 8; ++kt) {
    const int k0 = kt * 64;
#pragma unroll
    for (int i = 0; i < 4; i++)
      gload_lds16(A + (m0 + srow + i * 8) * 512 + k0 + schunk,
                  &As[wv * 32 + i * 8][0]);
#pragma unroll
    for (int i = 0; i < 4; i++)
      gload_lds16(W + (size_t)(o0 + srow + i * 8) * 512 + k0 + schunk,
                  &Ws[wv * 32 + i * 8][0]);
    __syncthreads();
    const int fr = lane & 15;
#pragma unroll
    for (int kk = 0; kk < 2; ++kk) {
      const int ch = kk * 4 + (lane >> 4);
      const int cb = ((ch ^ (lane & 7)) << 3);
      uint4 ar[4], br[4];
#pragma unroll
      for (int mi = 0; mi < 4; mi++)
        ar[mi] = *reinterpret_cast<const uint4*>(&As[wr * 64 + mi * 16 + fr][cb]);
#pragma unroll
      for (int ni = 0; ni < 4; ni++)
        br[ni] = *reinterpret_cast<const uint4*>(&Ws[wc * 64 + ni * 16 + fr][cb]);
#pragma unroll
      for (int mi = 0; mi < 4; mi++)
#pragma unroll
        for (int ni = 0; ni < 4; ni++)
          acc[mi][ni] = __builtin_amdgcn_mfma_f32_16x16x32_bf16(
              __builtin_bit_cast(bf16x8, ar[mi]),
              __builtin_bit_cast(bf16x8, br[ni]), acc[mi][ni], 0, 0, 0);
    }
    __syncthreads();
  }

  const int colbase = lane & 15;
  const int rowgrp  = (lane >> 4) * 4;
#pragma unroll
  for (int mi = 0; mi < 4; mi++) {
#pragma unroll
    for (int r = 0; r < 4; r++) {
      const size_t t = m0 + wr * 64 + mi * 16 + rowgrp + r;
      ushort_t* rowp = out_qkv + t * 1536;
#pragma unroll
      for (int ni = 0; ni < 4; ni++) {
        const int o = o0 + wc * 64 + ni * 16 + colbase;
        rowp[o] = f2bf(acc[mi][ni][r] + bias[o]);
      }
    }
  }
}

// ---------------------------------------------------------------------------
// GEMM2: out[m][o] = sum_k A[m][k]*W[o][k] + bias[o]  (bf16 in, fp32 out)
// R1-proven structure, unchanged.
// ---------------------------------------------------------------------------
__global__ __launch_bounds__(256) void k_gemmB(const ushort_t* __restrict__ A,
                                               const ushort_t* __restrict__ W,
                                               const float* __restrict__ bias,
                                               float* __restrict__ out_f,
                                               int nt_o) {
  __shared__ __align__(16) ushort_t As[128][64];
  __shared__ __align__(16) ushort_t Ws[128][64];

  const int tid  = threadIdx.x;
  const int lane = tid & 63;
  const int wv   = tid >> 6;
  const int wr   = wv >> 1, wc = wv & 1;

  const int cpx = gridDim.x >> 3;
  const int lid = (blockIdx.x & 7) * cpx + (blockIdx.x >> 3);
  const int bm  = lid / nt_o;
  const int bo  = lid - bm * nt_o;
  const size_t m0 = (size_t)bm * 128;
  const int o0    = bo * 128;

  f32x4 acc[4][4];
#pragma unroll
  for (int i = 0; i < 4; i++)
#pragma unroll
    for (int j = 0; j < 4; j++) acc[i][j] = f32x4{0.f, 0.f, 0.f, 0.f};

  const int srow   = wv * 32 + (lane >> 3);
  const int schunk = (((lane & 7) ^ (lane >> 3)) * 8);

  for (int kt = 0; kt < 8; ++kt) {
    const int k0 = kt * 64;
#pragma unroll
    for (int i = 0; i < 4; i++)
      gload_lds16(A + (m0 + srow + i * 8) * 512 + k0 + schunk,
                  &As[wv * 32 + i * 8][0]);
#pragma unroll
    for (int i = 0; i < 4; i++)
      gload_lds16(W + (size_t)(o0 + srow + i * 8) * 512 + k0 + schunk,
                  &Ws[wv * 32 + i * 8][0]);
    __syncthreads();
    const int fr = lane & 15;
#pragma unroll
    for (int kk = 0; kk < 2; ++kk) {
      const int ch = kk * 4 + (lane >> 4);
      const int cb = ((ch ^ (lane & 7)) << 3);
      uint4 ar[4], br[4];
#pragma unroll
      for (int mi = 0; mi < 4; mi++)
        ar[mi] = *reinterpret_cast<const uint4*>(&As[wr * 64 + mi * 16 + fr][cb]);
#pragma unroll
      for (int ni = 0; ni < 4; ni++)
        br[ni] = *reinterpret_cast<const uint4*>(&Ws[wc * 64 + ni * 16 + fr][cb]);
#pragma unroll
      for (int mi = 0; mi < 4; mi++)
#pragma unroll
        for (int ni = 0; ni < 4; ni++)
          acc[mi][ni] = __builtin_amdgcn_mfma_f32_16x16x32_bf16(
              __builtin_bit_cast(bf16x8, ar[mi]),
              __builtin_bit_cast(bf16x8, br[ni]), acc[mi][ni], 0, 0, 0);
    }
    __syncthreads();
  }

  const int colbase = lane & 15;
  const int rowgrp  = (lane >> 4) * 4;
#pragma unroll
  for (int ni = 0; ni < 4; ni++) {
    const int o = o0 + wc * 64 + ni * 16 + colbase;
    const float bv = bias[o];
#pragma unroll
    for (int mi = 0; mi < 4; mi++) {
      const size_t mrow = m0 + wr * 64 + mi * 16 + rowgrp;
#pragma unroll
      for (int r = 0; r < 4; r++)
        out_f[(mrow + r) * 512 + o] = acc[mi][ni][r] + bv;
    }
  }
}

// ---------------------------------------------------------------------------
// Attention v5: wave-per-head, token-major qkv, wave-private LDS only.
// Ps is a QUARTER buffer [16][64] per wave, reused per mt: for each mt-tile
// {S MFMA -> exp -> Ps write -> lgkm fence -> PV(+ones rowsum) -> store}.
// LDS = Vt 16KB + Ps 8KB = 24KB -> 5-6 blocks/CU. No __syncthreads at all.
// ---------------------------------------------------------------------------
__global__ __launch_bounds__(256) void k_attn4(const ushort_t* __restrict__ qkv,
                                               const float* __restrict__ mask,
                                               ushort_t* __restrict__ aout) {
  __shared__ __align__(16) ushort_t Vt[4][32][64];   // per-wave V^T (swizzled)
  __shared__ __align__(16) ushort_t Ps[4][16][64];   // per-wave P quarter-tile

  const int tid  = threadIdx.x;
  const int lane = tid & 63;
  const int wv   = tid >> 6;
  const int blk  = blockIdx.x;
  const int b    = blk >> 2;
  const int h    = (blk & 3) * 4 + wv;
  const int w    = b & 63;
  const size_t tb = (size_t)b * 49 * 1536 + (size_t)h * 32;
  const ushort_t* qb = qkv + tb;          // + n*1536 + d
  const ushort_t* kb = qkv + tb + 512;
  const ushort_t* vb = qkv + tb + 1024;

  // zero own Vt (pad cols must be finite), then transposed V write.
  // Wave-private: DS pipe is in-order per wave, no cross-wave barrier needed.
  {
    uint4* vz = reinterpret_cast<uint4*>(&Vt[wv][0][0]);
#pragma unroll
    for (int i = 0; i < 4; i++) vz[i * 64 + lane] = make_uint4(0, 0, 0, 0);
  }
#pragma unroll
  for (int i = 0; i < 4; i++) {
    const int e = lane + (i << 6);
    if (e < 196) {
      const int n = e >> 2, d0 = (e & 3) * 8;
      uint4 raw = *reinterpret_cast<const uint4*>(vb + (size_t)n * 1536 + d0);
      us8 ev = __builtin_bit_cast(us8, raw);
#pragma unroll
      for (int j = 0; j < 8; j++)
        Vt[wv][d0 + j][(((n >> 3) ^ j) << 3) | (n & 7)] = ev[j];
    }
  }
  lds_fence();   // Vt writes -> vf reads (wave-local)

  const int arow = lane & 15;
  const int kc   = (lane >> 4) * 8;
  const int rg   = (lane >> 4) * 4;

  // V fragments (read once, reused for all mt)
  uint4 vf0[2], vf1[2];
#pragma unroll
  for (int kk = 0; kk < 2; kk++) {
    const int ch = kk * 4 + (lane >> 4);
    const int cb = ((ch ^ (lane & 7)) << 3);
    vf0[kk] = *reinterpret_cast<const uint4*>(&Vt[wv][arow][cb]);
    vf1[kk] = *reinterpret_cast<const uint4*>(&Vt[wv][16 + arow][cb]);
  }

  uint4 kf[4];
#pragma unroll
  for (int ni = 0; ni < 4; ni++)
    kf[ni] = *reinterpret_cast<const uint4*>(kb + (size_t)(ni * 16 + arow) * 1536 + kc);

  bf16x8 ones;
#pragma unroll
  for (int i = 0; i < 8; i++) ones[i] = (__bf16)1.0f;

#pragma unroll
  for (int mt = 0; mt < 4; mt++) {
    // ---- S for this mt, exp, store into quarter buffer ----
    {
      uint4 qraw = *reinterpret_cast<const uint4*>(qb + (size_t)(mt * 16 + arow) * 1536 + kc);
      bf16x8 qa = __builtin_bit_cast(bf16x8, qraw);
      f32x4 s[4];
#pragma unroll
      for (int ni = 0; ni < 4; ni++) {
        f32x4 z = {0.f, 0.f, 0.f, 0.f};
        s[ni] = __builtin_amdgcn_mfma_f32_16x16x32_bf16(
            qa, __builtin_bit_cast(bf16x8, kf[ni]), z, 0, 0, 0);
      }
#pragma unroll
      for (int r = 0; r < 4; r++) {
        const int qr = mt * 16 + rg + r;
        const int prow = rg + r;
#pragma unroll
        for (int ni = 0; ni < 4; ni++) {
          const int col = ni * 16 + arow;
          float p;
          if (qr < 49 && col < 49)
            p = __expf(s[ni][r] * SCALE_F + mask[(size_t)w * 2401 + qr * 49 + col]);
          else
            p = 0.f;
          const int pcol = ni * 16 + arow;
          Ps[wv][prow][(((pcol >> 3) ^ (prow & 7)) << 3) | (pcol & 7)] = f2bf(p);
        }
      }
    }
    lds_fence();   // Ps writes -> Ps reads (wave-local RAW)

    // ---- PV for this mt (+ ones-MFMA rowsum) ----
    {
      f32x4 o0 = {0.f, 0.f, 0.f, 0.f}, o1 = {0.f, 0.f, 0.f, 0.f};
      f32x4 o2 = {0.f, 0.f, 0.f, 0.f};
#pragma unroll
      for (int kk = 0; kk < 2; kk++) {
        const int ch = kk * 4 + (lane >> 4);
        const int cb = ((ch ^ (lane & 7)) << 3);
        uint4 praw = *reinterpret_cast<const uint4*>(&Ps[wv][arow][cb]);
        bf16x8 pa = __builtin_bit_cast(bf16x8, praw);
        o0 = __builtin_amdgcn_mfma_f32_16x16x32_bf16(
            pa, __builtin_bit_cast(bf16x8, vf0[kk]), o0, 0, 0, 0);
        o1 = __builtin_amdgcn_mfma_f32_16x16x32_bf16(
            pa, __builtin_bit_cast(bf16x8, vf1[kk]), o1, 0, 0, 0);
        o2 = __builtin_amdgcn_mfma_f32_16x16x32_bf16(pa, ones, o2, 0, 0, 0);
      }
#pragma unroll
      for (int r = 0; r < 4; r++) {
        const int qr = mt * 16 + rg + r;
        if (qr < 49) {
          const float inv = 1.f / o2[r];
          aout[((size_t)b * 49 + qr) * 512 + h * 32 + arow]      = f2bf(o0[r] * inv);
          aout[((size_t)b * 49 + qr) * 512 + h * 32 + 16 + arow] = f2bf(o1[r] * inv);
        }
      }
    }
    // WAR (next-mt Ps writes vs this-mt reads) is safe: per-wave DS pipe is
    // in-order and the compiler preserves order of same-array LDS accesses.
  }
}

// ---------------------------------------------------------------------------
// launch
// ---------------------------------------------------------------------------
extern "C" void kernel_launch(void* const* d_in, const int* in_sizes, int n_in,
                              void* d_out, int out_size, void* d_ws, size_t ws_size,
                              hipStream_t stream) {
  const float* x      = (const float*)d_in[0];
  const float* mask   = (const float*)d_in[1];
  const float* W_qkv  = (const float*)d_in[2];
  const float* b_qkv  = (const float*)d_in[3];
  const float* W_proj = (const float*)d_in[4];
  const float* b_proj = (const float*)d_in[5];
  float* out = (float*)d_out;

  // ws layout (bf16 elems): xb | qkv token-major | attn_out | Wqkv_b | Wproj_b
  ushort_t* ws     = (ushort_t*)d_ws;
  ushort_t* xb     = ws;                                  // 51,380,224
  ushort_t* qkvb   = ws + 51380224UL;                     // 154,140,672
  ushort_t* aoutb  = ws + 205520896UL;                    // 51,380,224
  ushort_t* wqkvb  = ws + 256901120UL;                    // 786,432
  ushort_t* wprojb = ws + 257687552UL;                    // 262,144

  const int n4x = 51380224 / 4, n4q = 786432 / 4, n4p = 262144 / 4;
  k_cvt<<<(n4x + 255) / 256, 256, 0, stream>>>(x, xb, n4x);
  k_cvt<<<(n4q + 255) / 256, 256, 0, stream>>>(W_qkv, wqkvb, n4q);
  k_cvt<<<(n4p + 255) / 256, 256, 0, stream>>>(W_proj, wprojb, n4p);

  // GEMM1: [100352,512] x [1536,512]^T -> token-major qkv.
  k_gemm1<<<784 * 12, 256, 0, stream>>>(xb, wqkvb, b_qkv, qkvb);

  // attention: block = 4 heads, wave = 1 head
  k_attn4<<<2048 * 4, 256, 0, stream>>>(qkvb, mask, aoutb);

  // GEMM2: [100352,512] x [512,512]^T + bias -> fp32 out.
  k_gemmB<<<784 * 4, 256, 0, stream>>>(aoutb, wprojb, b_proj, out, 4);
}